// Round 3
// baseline (61.211 us; speedup 1.0000x reference)
//
#include <hip/hip_runtime.h>

typedef __bf16 bf16x8 __attribute__((ext_vector_type(8)));
typedef float f32x4 __attribute__((ext_vector_type(4)));
typedef unsigned short ushort8 __attribute__((ext_vector_type(8)));

#define D 128

static __device__ __forceinline__ unsigned short f32_to_bf16(float f) {
  unsigned int u = __float_as_uint(f);
  u += 0x7fffu + ((u >> 16) & 1u);   // RNE
  return (unsigned short)(u >> 16);
}

// One block = 16 rows, 16 lanes per row. Normalizes both matrices to bf16 in ws
// and atomically accumulates the diagonal correction
// sum_i (1 - cos_ii - relu(cos_ii))  (exact f32) into diag_acc.
__global__ void normalize_diag_kernel(const float* __restrict__ anc,
                                      const float* __restrict__ pos,
                                      unsigned short* __restrict__ wsA,
                                      unsigned short* __restrict__ wsP,
                                      float* __restrict__ diag_acc) {
  __shared__ float rowc[16];
  const int t = threadIdx.x;
  const int rl = t >> 4, l16 = t & 15;
  const int row = blockIdx.x * 16 + rl;
  const float* ar = anc + (size_t)row * D + l16 * 8;
  const float* pr = pos + (size_t)row * D + l16 * 8;
  float4 a0 = *(const float4*)ar, a1 = *(const float4*)(ar + 4);
  float4 p0 = *(const float4*)pr, p1 = *(const float4*)(pr + 4);
  float av[8] = {a0.x, a0.y, a0.z, a0.w, a1.x, a1.y, a1.z, a1.w};
  float pv[8] = {p0.x, p0.y, p0.z, p0.w, p1.x, p1.y, p1.z, p1.w};
  float ssa = 0.f, ssp = 0.f;
#pragma unroll
  for (int k = 0; k < 8; ++k) { ssa += av[k] * av[k]; ssp += pv[k] * pv[k]; }
#pragma unroll
  for (int off = 1; off < 16; off <<= 1) {
    ssa += __shfl_xor(ssa, off);
    ssp += __shfl_xor(ssp, off);
  }
  const float sa = 1.f / fmaxf(sqrtf(ssa), 1e-8f);
  const float sp = 1.f / fmaxf(sqrtf(ssp), 1e-8f);
  float dot = 0.f;
  ushort8 a8, p8;
#pragma unroll
  for (int k = 0; k < 8; ++k) {
    const float an = av[k] * sa, pn = pv[k] * sp;
    dot += an * pn;
    a8[k] = f32_to_bf16(an);
    p8[k] = f32_to_bf16(pn);
  }
  *(ushort8*)(wsA + (size_t)row * D + l16 * 8) = a8;
  *(ushort8*)(wsP + (size_t)row * D + l16 * 8) = p8;
#pragma unroll
  for (int off = 1; off < 16; off <<= 1) dot += __shfl_xor(dot, off);
  if (l16 == 0) rowc[rl] = 1.f - dot - fmaxf(dot, 0.f);
  __syncthreads();
  if (t == 0) {
    float s = 0.f;
#pragma unroll
    for (int i = 0; i < 16; ++i) s += rowc[i];
    atomicAdd(diag_acc, s);
  }
}

// Persistent no-LDS GEMM: 256 blocks (1/CU), 8 waves each.
// Wave subtile 64x128; A-fragments (64 VGPR) loaded once from L2 and reused
// across 4 column tiles; B-fragments streamed from L2 (perfectly 64B-line
// coalesced: each wave instr reads 16 rows x 64 contiguous bytes).
// No LDS, no barriers. Epilogue: relu-sum -> device atomics; last block
// finalizes (adds diag correction, scales, writes d_out).
__global__ __launch_bounds__(512, 2) void gemm_relu_sum_kernel(
    const unsigned short* __restrict__ wsA,
    const unsigned short* __restrict__ wsP,
    float* __restrict__ relu_acc, float* __restrict__ diag_acc,
    int* __restrict__ counter, float* __restrict__ out, float invBB,
    int nBlocks) {
  __shared__ float wpart[8];
  const int tid = threadIdx.x;
  const int w = tid >> 6, l = tid & 63;
  const int r16 = l & 15, kg = l >> 4;
  const int wrow = w >> 1, wcol = w & 1;   // 4 x 2 waves -> block tile 256x256
  const int rp = blockIdx.x >> 3;          // row panel 0..31 (256 rows)
  const int cq = blockIdx.x & 7;           // column quad 0..7 (4 tiles each)

  // A fragments: rows rp*256 + wrow*64 + m*16 + r16, 16B chunk (ks*4+kg)
  const char* gA = (const char*)wsA;
  const char* gP = (const char*)wsP;
  bf16x8 af[4][4];
#pragma unroll
  for (int m = 0; m < 4; ++m) {
    const int r = rp * 256 + wrow * 64 + m * 16 + r16;
#pragma unroll
    for (int ks = 0; ks < 4; ++ks)
      af[m][ks] = *(const bf16x8*)(gA + (size_t)r * 256 + (ks * 4 + kg) * 16);
  }

  float s = 0.f;
#pragma unroll
  for (int t = 0; t < 4; ++t) {
    const int cbase = (cq * 4 + t) * 256 + wcol * 128;
    f32x4 acc[4][8] = {};
#pragma unroll
    for (int ks = 0; ks < 4; ++ks) {
      bf16x8 bfr[8];
#pragma unroll
      for (int n = 0; n < 8; ++n) {
        const int r = cbase + n * 16 + r16;
        bfr[n] = *(const bf16x8*)(gP + (size_t)r * 256 + (ks * 4 + kg) * 16);
      }
#pragma unroll
      for (int m = 0; m < 4; ++m)
#pragma unroll
        for (int n = 0; n < 8; ++n)
          acc[m][n] = __builtin_amdgcn_mfma_f32_16x16x32_bf16(
              af[m][ks], bfr[n], acc[m][n], 0, 0, 0);
    }
    // relu-sum this tile (layout-oblivious)
#pragma unroll
    for (int m = 0; m < 4; ++m)
#pragma unroll
      for (int n = 0; n < 8; ++n)
#pragma unroll
        for (int q = 0; q < 4; ++q) s += fmaxf(acc[m][n][q], 0.f);
  }

#pragma unroll
  for (int off = 32; off >= 1; off >>= 1) s += __shfl_xor(s, off);
  if (l == 0) wpart[w] = s;
  __syncthreads();
  if (tid == 0) {
    float b = 0.f;
#pragma unroll
    for (int i = 0; i < 8; ++i) b += wpart[i];
    atomicAdd(relu_acc, b);
    __threadfence();
    const int ticket = atomicAdd(counter, 1);
    if (ticket == nBlocks - 1) {
      __threadfence();
      const float rtot = atomicAdd(relu_acc, 0.f);   // coherent read
      const float dtot = atomicAdd(diag_acc, 0.f);
      out[0] = (rtot + dtot) * invBB;
    }
  }
}

extern "C" void kernel_launch(void* const* d_in, const int* in_sizes, int n_in,
                              void* d_out, int out_size, void* d_ws, size_t ws_size,
                              hipStream_t stream) {
  const float* pos = (const float*)d_in[0];  // hid_positive
  const float* anc = (const float*)d_in[1];  // hid_anchor
  const int B = in_sizes[0] / D;             // 8192

  char* ws = (char*)d_ws;
  unsigned short* wsA = (unsigned short*)ws;                         // B*D bf16
  unsigned short* wsP = (unsigned short*)(ws + (size_t)B * D * 2);   // B*D bf16
  float* relu_acc = (float*)(ws + (size_t)B * D * 4);
  float* diag_acc = relu_acc + 1;
  int* counter = (int*)(relu_acc + 2);

  hipMemsetAsync(relu_acc, 0, 12, stream);   // relu_acc, diag_acc, counter = 0
  normalize_diag_kernel<<<B / 16, 256, 0, stream>>>(anc, pos, wsA, wsP, diag_acc);
  const int nBlocks = 256;                   // persistent: 1 block/CU
  const float invBB = 1.0f / ((float)B * (float)B);
  gemm_relu_sum_kernel<<<nBlocks, 512, 0, stream>>>(wsA, wsP, relu_acc, diag_acc,
                                                    counter, (float*)d_out, invBB,
                                                    nBlocks);
}

// Round 4
// 29.956 us; speedup vs baseline: 2.0433x; 2.0433x over previous
//
#include <hip/hip_runtime.h>

typedef __bf16 bf16x8 __attribute__((ext_vector_type(8)));
typedef float f32x4 __attribute__((ext_vector_type(4)));
typedef unsigned short ushort8 __attribute__((ext_vector_type(8)));

#define D 128

static __device__ __forceinline__ unsigned short f32_to_bf16(float f) {
  unsigned int u = __float_as_uint(f);
  u += 0x7fffu + ((u >> 16) & 1u);   // RNE
  return (unsigned short)(u >> 16);
}

// One block = 16 rows, 16 lanes per row. Normalizes both matrices to bf16 in ws
// and writes this block's diagonal correction sum_i (1 - cos_ii - relu(cos_ii))
// to diagP[blockIdx.x] (deterministic, no atomics, no zero-init needed).
__global__ void normalize_diag_kernel(const float* __restrict__ anc,
                                      const float* __restrict__ pos,
                                      unsigned short* __restrict__ wsA,
                                      unsigned short* __restrict__ wsP,
                                      float* __restrict__ diagP) {
  __shared__ float rowc[16];
  const int t = threadIdx.x;
  const int rl = t >> 4, l16 = t & 15;
  const int row = blockIdx.x * 16 + rl;
  const float* ar = anc + (size_t)row * D + l16 * 8;
  const float* pr = pos + (size_t)row * D + l16 * 8;
  float4 a0 = *(const float4*)ar, a1 = *(const float4*)(ar + 4);
  float4 p0 = *(const float4*)pr, p1 = *(const float4*)(pr + 4);
  float av[8] = {a0.x, a0.y, a0.z, a0.w, a1.x, a1.y, a1.z, a1.w};
  float pv[8] = {p0.x, p0.y, p0.z, p0.w, p1.x, p1.y, p1.z, p1.w};
  float ssa = 0.f, ssp = 0.f;
#pragma unroll
  for (int k = 0; k < 8; ++k) { ssa += av[k] * av[k]; ssp += pv[k] * pv[k]; }
#pragma unroll
  for (int off = 1; off < 16; off <<= 1) {
    ssa += __shfl_xor(ssa, off);
    ssp += __shfl_xor(ssp, off);
  }
  const float sa = 1.f / fmaxf(sqrtf(ssa), 1e-8f);
  const float sp = 1.f / fmaxf(sqrtf(ssp), 1e-8f);
  float dot = 0.f;
  ushort8 a8, p8;
#pragma unroll
  for (int k = 0; k < 8; ++k) {
    const float an = av[k] * sa, pn = pv[k] * sp;
    dot += an * pn;
    a8[k] = f32_to_bf16(an);
    p8[k] = f32_to_bf16(pn);
  }
  *(ushort8*)(wsA + (size_t)row * D + l16 * 8) = a8;
  *(ushort8*)(wsP + (size_t)row * D + l16 * 8) = p8;
#pragma unroll
  for (int off = 1; off < 16; off <<= 1) dot += __shfl_xor(dot, off);
  if (l16 == 0) rowc[rl] = 1.f - dot - fmaxf(dot, 0.f);
  __syncthreads();
  if (t == 0) {
    float s = 0.f;
#pragma unroll
    for (int i = 0; i < 16; ++i) s += rowc[i];
    diagP[blockIdx.x] = s;
  }
}

// Persistent GEMM: 256 blocks (1/CU), 8 waves (4 wrow x 2 wcol).
// Block = 256-row panel x 1024-col group, looped as 8 column tiles of 128.
// A (256x128 bf16, 64KB) staged to LDS once with swizzled global source,
// then A-fragments hoisted to 64 VGPRs and reused for all 8 tiles.
// B tiles (128x128, 32KB) double-buffered: stage t+1, compute t, syncthreads
// (drain is free: loads issued ~2000cy earlier). Epilogue: relu-sum ->
// deterministic per-block partial (layout-oblivious, no atomics).
__global__ __launch_bounds__(512, 2) void gemm_relu_sum_kernel(
    const unsigned short* __restrict__ wsA,
    const unsigned short* __restrict__ wsP,
    float* __restrict__ partials) {
  __shared__ __align__(16) unsigned short ldsA[256 * 128];      // 64 KB
  __shared__ __align__(16) unsigned short ldsB[2][128 * 128];   // 2 x 32 KB
  __shared__ float wpart[8];
  const int tid = threadIdx.x;
  const int w = tid >> 6, l = tid & 63;
  const int r16 = l & 15, kg = l >> 4;
  const int wrow = w >> 1, wcol = w & 1;   // wave tile 64 rows x 64 cols
  const int rp = blockIdx.x >> 3;          // row panel 0..31
  const int cg = blockIdx.x & 7;           // col group 0..7 (XCD-pinned)

  const char* gA = (const char*)(wsA + (size_t)rp * 256 * D);
  const char* gP = (const char*)wsP;
  char* lA = (char*)ldsA;

  // ---- prologue: stage A (8 rounds) + B tile 0 (4 rounds), swizzled source
#pragma unroll
  for (int it = 0; it < 8; ++it) {
    const int g = it * 512 + tid;            // 16B chunk 0..4095
    const int row = g >> 4, slot = g & 15;
    const int goff = row * 256 + (slot ^ (row & 7)) * 16;
    const int lbase = (it * 512 + w * 64) * 16;
    __builtin_amdgcn_global_load_lds(
        (const __attribute__((address_space(1))) char*)(gA + goff),
        (__attribute__((address_space(3))) char*)(lA + lbase), 16, 0, 0);
  }
  {
    char* lB = (char*)ldsB[0];
    const size_t cbase = (size_t)(cg * 1024) * 256;   // byte row base in wsP
#pragma unroll
    for (int it = 0; it < 4; ++it) {
      const int g = it * 512 + tid;          // 16B chunk 0..2047
      const int row = g >> 4, slot = g & 15;
      const size_t goff = cbase + row * 256 + (slot ^ (row & 7)) * 16;
      const int lbase = (it * 512 + w * 64) * 16;
      __builtin_amdgcn_global_load_lds(
          (const __attribute__((address_space(1))) char*)(gP + goff),
          (__attribute__((address_space(3))) char*)(lB + lbase), 16, 0, 0);
    }
  }
  __syncthreads();

  // ---- hoist A fragments to registers (reused across all 8 column tiles)
  bf16x8 af[4][4];
#pragma unroll
  for (int m = 0; m < 4; ++m) {
    const int r = wrow * 64 + m * 16 + r16;
#pragma unroll
    for (int ks = 0; ks < 4; ++ks) {
      const int ck = ks * 4 + kg;
      af[m][ks] = *(const bf16x8*)(lA + r * 256 + ((ck ^ (r & 7)) * 16));
    }
  }

  float s = 0.f;
  for (int t = 0; t < 8; ++t) {
    // stage next B tile into the other buffer (latency hides under compute)
    if (t < 7) {
      char* lB = (char*)ldsB[(t + 1) & 1];
      const size_t cbase = (size_t)(cg * 1024 + (t + 1) * 128) * 256;
#pragma unroll
      for (int it = 0; it < 4; ++it) {
        const int g = it * 512 + tid;
        const int row = g >> 4, slot = g & 15;
        const size_t goff = cbase + row * 256 + (slot ^ (row & 7)) * 16;
        const int lbase = (it * 512 + w * 64) * 16;
        __builtin_amdgcn_global_load_lds(
            (const __attribute__((address_space(1))) char*)(gP + goff),
            (__attribute__((address_space(3))) char*)(lB + lbase), 16, 0, 0);
      }
    }

    // compute on current buffer
    const char* lB = (const char*)ldsB[t & 1];
    bf16x8 bfr[4][4];
#pragma unroll
    for (int n = 0; n < 4; ++n) {
      const int r = wcol * 64 + n * 16 + r16;
#pragma unroll
      for (int ks = 0; ks < 4; ++ks) {
        const int ck = ks * 4 + kg;
        bfr[n][ks] = *(const bf16x8*)(lB + r * 256 + ((ck ^ (r & 7)) * 16));
      }
    }
    f32x4 acc[4][4] = {};
#pragma unroll
    for (int ks = 0; ks < 4; ++ks)
#pragma unroll
      for (int m = 0; m < 4; ++m)
#pragma unroll
        for (int n = 0; n < 4; ++n)
          acc[m][n] = __builtin_amdgcn_mfma_f32_16x16x32_bf16(
              af[m][ks], bfr[n][ks], acc[m][n], 0, 0, 0);
    // relu-sum this tile (layout-oblivious)
#pragma unroll
    for (int m = 0; m < 4; ++m)
#pragma unroll
      for (int n = 0; n < 4; ++n)
#pragma unroll
        for (int q = 0; q < 4; ++q) s += fmaxf(acc[m][n][q], 0.f);

    __syncthreads();   // drains staged loads (issued ~2000cy ago) + barrier
  }

#pragma unroll
  for (int off = 32; off >= 1; off >>= 1) s += __shfl_xor(s, off);
  if (l == 0) wpart[w] = s;
  __syncthreads();
  if (tid == 0) {
    float b = 0.f;
#pragma unroll
    for (int i = 0; i < 8; ++i) b += wpart[i];
    partials[blockIdx.x] = b;
  }
}

__global__ void finalize_kernel(const float* __restrict__ partials, int nPart,
                                const float* __restrict__ diagP, int nDiag,
                                float* __restrict__ out, float invBB) {
  __shared__ float wsum[4];
  const int t = threadIdx.x;
  float s = 0.f;
  for (int i = t; i < nPart; i += 256) s += partials[i];
  for (int i = t; i < nDiag; i += 256) s += diagP[i];
#pragma unroll
  for (int off = 32; off >= 1; off >>= 1) s += __shfl_xor(s, off);
  if ((t & 63) == 0) wsum[t >> 6] = s;
  __syncthreads();
  if (t == 0) out[0] = (wsum[0] + wsum[1] + wsum[2] + wsum[3]) * invBB;
}

extern "C" void kernel_launch(void* const* d_in, const int* in_sizes, int n_in,
                              void* d_out, int out_size, void* d_ws, size_t ws_size,
                              hipStream_t stream) {
  const float* pos = (const float*)d_in[0];  // hid_positive
  const float* anc = (const float*)d_in[1];  // hid_anchor
  const int B = in_sizes[0] / D;             // 8192

  char* ws = (char*)d_ws;
  unsigned short* wsA = (unsigned short*)ws;                         // B*D bf16
  unsigned short* wsP = (unsigned short*)(ws + (size_t)B * D * 2);   // B*D bf16
  float* partials = (float*)(ws + (size_t)B * D * 4);
  const int nBlocks = 256;                   // persistent: 1 block/CU
  float* diagP = partials + nBlocks;
  const int nDiag = B / 16;                  // 512

  normalize_diag_kernel<<<nDiag, 256, 0, stream>>>(anc, pos, wsA, wsP, diagP);
  gemm_relu_sum_kernel<<<nBlocks, 512, 0, stream>>>(wsA, wsP, partials);
  const float invBB = 1.0f / ((float)B * (float)B);
  finalize_kernel<<<1, 256, 0, stream>>>(partials, nBlocks, diagP, nDiag,
                                         (float*)d_out, invBB);
}